// Round 5
// baseline (48527.643 us; speedup 1.0000x reference)
//
#include <hip/hip_runtime.h>
#include <hip/hip_bf16.h>

using bf16 = __hip_bfloat16;

// Problem dims (fixed by the reference)
constexpr int B  = 128;
constexpr int SP = 128;
constexpr int SH = 64;
constexpr int H  = 1024;
constexpr int E  = 300;
constexpr int NC = 4;
constexpr int G4H  = 4 * H;     // 4096
constexpr int KCAT = E + H;     // 1324

__device__ __forceinline__ float sigf(float x) { return 1.0f / (1.0f + __expf(-x)); }
// tanh via exp; 1 - 2/(e+1) is inf-safe on both ends
__device__ __forceinline__ float tanh_fast(float x) {
    float e = __expf(2.0f * x);
    return 1.0f - 2.0f / (e + 1.0f);
}

// ---------------------------------------------------------------------------
// Generic fp32 SGEMM: C[M,N] (+)= A[M,K] * Bm[K,N]  (Bm row-major [K,N])
// Tile 32x64, BK=16, 256 threads, 2x4 per thread. fp32 accumulate.
// ---------------------------------------------------------------------------
template<bool ACC>
__global__ void sgemm_kernel(const float* __restrict__ A, int lda,
                             const float* __restrict__ Bm, int ldb,
                             float* __restrict__ C, int ldc,
                             int M, int N, int K)
{
    constexpr int BM = 32, BN = 64, BK = 16, TM = 2, TN = 4;
    __shared__ float As[BK][BM + 4];
    __shared__ float Bs[BK][BN + 4];
    const int tid = threadIdx.x;
    const int tx = tid & 15;   // N dir
    const int ty = tid >> 4;   // M dir
    const int n0 = blockIdx.x * BN;
    const int m0 = blockIdx.y * BM;

    float acc[TM][TN];
#pragma unroll
    for (int i = 0; i < TM; ++i)
#pragma unroll
        for (int j = 0; j < TN; ++j) acc[i][j] = 0.f;

    for (int k0 = 0; k0 < K; k0 += BK) {
        {   // A tile: 32 x 16
            int ak = tid & 15, am = tid >> 4;
#pragma unroll
            for (int r = 0; r < 2; ++r) {
                int m = m0 + am + r * 16;
                int k = k0 + ak;
                As[ak][am + r * 16] = (k < K) ? A[(size_t)m * lda + k] : 0.f;
            }
        }
        {   // B tile: 16 x 64 from [K,N] fp32
            int bn = tid & 63, bk0 = tid >> 6;
#pragma unroll
            for (int r = 0; r < 4; ++r) {
                int k = k0 + bk0 + r * 4;
                Bs[bk0 + r * 4][bn] = (k < K) ? Bm[(size_t)k * ldb + n0 + bn] : 0.f;
            }
        }
        __syncthreads();
#pragma unroll
        for (int kk = 0; kk < BK; ++kk) {
            float a[TM], bv[TN];
#pragma unroll
            for (int i = 0; i < TM; ++i) a[i] = As[kk][ty * TM + i];
#pragma unroll
            for (int j = 0; j < TN; ++j) bv[j] = Bs[kk][tx * TN + j];
#pragma unroll
            for (int i = 0; i < TM; ++i)
#pragma unroll
                for (int j = 0; j < TN; ++j) acc[i][j] += a[i] * bv[j];
        }
        __syncthreads();
    }
#pragma unroll
    for (int i = 0; i < TM; ++i) {
        int m = m0 + ty * TM + i;
#pragma unroll
        for (int j = 0; j < TN; ++j) {
            int n = n0 + tx * TN + j;
            float v = acc[i][j];
            if (ACC) v += C[(size_t)m * ldc + n];
            C[(size_t)m * ldc + n] = v;
        }
    }
}

// ---------------------------------------------------------------------------
// LSTM gate pre-activations for one timestep (all weights fp32):
// g[b,j] = b_ih[j] + b_hh[j] + sum_e emb[tok[b,t],e]*w_ih[j,e] + sum_k h[b,k]*w_hh[j,k]
// A = [x_t | h] (K = E + H), B = [w_ih | w_hh] both [N,K] row-major.
// M=128 (b), N=4096 (j). Tile 32x64, BK=16.
// ---------------------------------------------------------------------------
__global__ void gates_kernel(const int* __restrict__ tokens, int t, int S,
                             const float* __restrict__ emb,
                             const float* __restrict__ h,
                             const float* __restrict__ w_ih,
                             const float* __restrict__ w_hh,
                             const float* __restrict__ b_ih,
                             const float* __restrict__ b_hh,
                             float* __restrict__ g)
{
    constexpr int BK = 16, TM = 2, TN = 4;
    __shared__ float As[BK][32 + 4];
    __shared__ float Bs[BK][64 + 4];
    const int tid = threadIdx.x;
    const int tx = tid & 15;
    const int ty = tid >> 4;
    const int n0 = blockIdx.x * 64;
    const int m0 = blockIdx.y * 32;

    float acc[TM][TN];
#pragma unroll
    for (int i = 0; i < TM; ++i)
#pragma unroll
        for (int j = 0; j < TN; ++j) acc[i][j] = 0.f;

    for (int k0 = 0; k0 < KCAT; k0 += BK) {
        {   // A tile: x from emb gather for k<E, else h
            int ak = tid & 15, am = tid >> 4;
#pragma unroll
            for (int r = 0; r < 2; ++r) {
                int m = m0 + am + r * 16;
                int k = k0 + ak;
                float v = 0.f;
                if (k < E) {
                    int tok = tokens[m * S + t];
                    v = emb[(size_t)tok * E + k];
                } else if (k < KCAT) {
                    v = h[m * H + (k - E)];
                }
                As[ak][am + r * 16] = v;
            }
        }
        {   // B tile from [N,K] row-major weights
            int bk = tid & 15, bn0 = tid >> 4;
#pragma unroll
            for (int r = 0; r < 4; ++r) {
                int n = n0 + bn0 + r * 16;
                int k = k0 + bk;
                float v = 0.f;
                if (k < E)          v = w_ih[(size_t)n * E + k];
                else if (k < KCAT)  v = w_hh[(size_t)n * H + (k - E)];
                Bs[bk][bn0 + r * 16] = v;
            }
        }
        __syncthreads();
#pragma unroll
        for (int kk = 0; kk < BK; ++kk) {
            float a[TM], bv[TN];
#pragma unroll
            for (int i = 0; i < TM; ++i) a[i] = As[kk][ty * TM + i];
#pragma unroll
            for (int j = 0; j < TN; ++j) bv[j] = Bs[kk][tx * TN + j];
#pragma unroll
            for (int i = 0; i < TM; ++i)
#pragma unroll
                for (int j = 0; j < TN; ++j) acc[i][j] += a[i] * bv[j];
        }
        __syncthreads();
    }
#pragma unroll
    for (int i = 0; i < TM; ++i) {
        int m = m0 + ty * TM + i;
#pragma unroll
        for (int j = 0; j < TN; ++j) {
            int n = n0 + tx * TN + j;
            g[(size_t)m * G4H + n] = acc[i][j] + b_ih[n] + b_hh[n];
        }
    }
}

// ---------------------------------------------------------------------------
// Pointwise LSTM cell + masked-carry bookkeeping (all fp32).
// premise_mode=1: seq_out laid out [B,SP,H] at column t; else [SH,B,H] at row t.
// ---------------------------------------------------------------------------
__global__ void lstm_cell_kernel(const float* __restrict__ g,
                                 float* __restrict__ h, float* __restrict__ c,
                                 float* __restrict__ hmask, float* __restrict__ cmask,
                                 float* __restrict__ seq_out, int premise_mode,
                                 const int* __restrict__ tokens, int t, int S)
{
    int idx = blockIdx.x * blockDim.x + threadIdx.x;
    if (idx >= B * H) return;
    int b = idx >> 10;          // H = 1024
    int k = idx & (H - 1);
    const float* gr = g + (size_t)b * G4H;
    float i_ = sigf(gr[k]);
    float f_ = sigf(gr[H + k]);
    float g_ = tanh_fast(gr[2 * H + k]);
    float o_ = sigf(gr[3 * H + k]);
    float c2 = f_ * c[idx] + i_ * g_;
    float h2 = o_ * tanh_fast(c2);
    c[idx] = c2;
    h[idx] = h2;
    float m = (tokens[b * S + t] != 0) ? 1.f : 0.f;
    float hm = m * h2 + (1.f - m) * hmask[idx];
    hmask[idx] = hm;
    if (cmask) {
        float cm = m * c2 + (1.f - m) * cmask[idx];
        cmask[idx] = cm;
    }
    if (premise_mode) seq_out[((size_t)b * SP + t) * H + k] = hm;
    else              seq_out[((size_t)t * B + b) * H + k] = hm;
}

// ---------------------------------------------------------------------------
// Attention score: s[b,p] = sum_h tanh(first[b,p,h]+second[b,h]) * w[h]  (+ -1000 on pads)
// ---------------------------------------------------------------------------
__global__ void score_kernel(const float* __restrict__ first,
                             const float* __restrict__ second,
                             const float* __restrict__ w,
                             const int* __restrict__ ptoks,
                             float* __restrict__ s)
{
    int bp = blockIdx.x;               // b*SP + p
    int b = bp >> 7;
    int p = bp & 127;
    const float* fr = first + (size_t)bp * H;
    const float* sr = second + (size_t)b * H;
    float acc = 0.f;
    for (int k = threadIdx.x; k < H; k += 256)
        acc += tanh_fast(fr[k] + sr[k]) * w[k];
    __shared__ float red[256];
    red[threadIdx.x] = acc;
    __syncthreads();
    for (int off = 128; off > 0; off >>= 1) {
        if (threadIdx.x < off) red[threadIdx.x] += red[threadIdx.x + off];
        __syncthreads();
    }
    if (threadIdx.x == 0) {
        float neg = (ptoks[b * SP + p] != 0) ? 0.f : -1000.f;
        s[bp] = red[0] + neg;
    }
}

// softmax over SP=128 per batch row, in place (128 threads / block)
__global__ void softmax_kernel(float* __restrict__ s)
{
    int b = blockIdx.x, tid = threadIdx.x;
    __shared__ float red[SP];
    float v = s[b * SP + tid];
    red[tid] = v;
    __syncthreads();
    for (int off = 64; off > 0; off >>= 1) {
        if (tid < off) red[tid] = fmaxf(red[tid], red[tid + off]);
        __syncthreads();
    }
    float mx = red[0];
    __syncthreads();
    float e = __expf(v - mx);
    red[tid] = e;
    __syncthreads();
    for (int off = 64; off > 0; off >>= 1) {
        if (tid < off) red[tid] += red[tid + off];
        __syncthreads();
    }
    s[b * SP + tid] = e / red[0];
}

// r_new[b,h] = sum_p alpha[b,p]*Y[b,p,h] + tanh(rwt[b,h]); masked carry into r
__global__ void r_update_kernel(const float* __restrict__ alpha,
                                const float* __restrict__ Y,
                                const float* __restrict__ rwt,
                                const int* __restrict__ htoks, int t,
                                float* __restrict__ r)
{
    int b = blockIdx.x;
    __shared__ float al[SP];
    if (threadIdx.x < SP) al[threadIdx.x] = alpha[b * SP + threadIdx.x];
    __syncthreads();
    float acc[4] = {0.f, 0.f, 0.f, 0.f};
    const float* Yb = Y + (size_t)b * SP * H;
    for (int p = 0; p < SP; ++p) {
        float a = al[p];
        const float* yr = Yb + (size_t)p * H;
#pragma unroll
        for (int j = 0; j < 4; ++j) acc[j] += a * yr[threadIdx.x + j * 256];
    }
    float m = (htoks[b * SH + t] != 0) ? 1.f : 0.f;
#pragma unroll
    for (int j = 0; j < 4; ++j) {
        int k = threadIdx.x + j * 256;
        float rnew = acc[j] + tanh_fast(rwt[(size_t)b * H + k]);
        r[(size_t)b * H + k] = m * rnew + (1.f - m) * r[(size_t)b * H + k];
    }
}

// logits[b,c] = fc_b[c] + sum_h tanh(pre[b,h]) * fc_w[c,h]; softmax over 4; fp32 out
__global__ void final_kernel(const float* __restrict__ pre,
                             const float* __restrict__ fc_w,
                             const float* __restrict__ fc_b,
                             float* __restrict__ out)
{
    int b = blockIdx.x;
    float acc[NC] = {0.f, 0.f, 0.f, 0.f};
    for (int k = threadIdx.x; k < H; k += 256) {
        float hs = tanh_fast(pre[(size_t)b * H + k]);
#pragma unroll
        for (int cc = 0; cc < NC; ++cc) acc[cc] += hs * fc_w[cc * H + k];
    }
    __shared__ float red[NC][256];
#pragma unroll
    for (int cc = 0; cc < NC; ++cc) red[cc][threadIdx.x] = acc[cc];
    __syncthreads();
    for (int off = 128; off > 0; off >>= 1) {
        if (threadIdx.x < off)
#pragma unroll
            for (int cc = 0; cc < NC; ++cc)
                red[cc][threadIdx.x] += red[cc][threadIdx.x + off];
        __syncthreads();
    }
    if (threadIdx.x == 0) {
        float l[NC], mx = -1e30f;
#pragma unroll
        for (int cc = 0; cc < NC; ++cc) { l[cc] = red[cc][0] + fc_b[cc]; mx = fmaxf(mx, l[cc]); }
        float sum = 0.f;
#pragma unroll
        for (int cc = 0; cc < NC; ++cc) { l[cc] = __expf(l[cc] - mx); sum += l[cc]; }
#pragma unroll
        for (int cc = 0; cc < NC; ++cc) out[b * NC + cc] = l[cc] / sum;
    }
}

extern "C" void kernel_launch(void* const* d_in, const int* in_sizes, int n_in,
                              void* d_out, int out_size, void* d_ws, size_t ws_size,
                              hipStream_t stream)
{
    // Established: inputs int32 / fp32; output fp32 (R4: err 0.871 -> 0.0996).
    // This round: ALL intermediates fp32 (R4's 0.0996 attributed to bf16
    // rounding of Y/first/outh amplified by the 64-step attention recurrence,
    // whose per-step weight spectral norm ~3 at H=1024, sigma=0.05).
    const int*   prem   = (const int*)d_in[0];
    const int*   hyp    = (const int*)d_in[1];
    const float* emb    = (const float*)d_in[2];
    const float* w_ih_p = (const float*)d_in[3];
    const float* w_hh_p = (const float*)d_in[4];
    const float* b_ih_p = (const float*)d_in[5];
    const float* b_hh_p = (const float*)d_in[6];
    const float* w_ih_h = (const float*)d_in[7];
    const float* w_hh_h = (const float*)d_in[8];
    const float* b_ih_h = (const float*)d_in[9];
    const float* b_hh_h = (const float*)d_in[10];
    const float* wy     = (const float*)d_in[11];
    const float* wh     = (const float*)d_in[12];
    const float* wr     = (const float*)d_in[13];
    const float* wv     = (const float*)d_in[14];   // w [H,1]
    const float* wt     = (const float*)d_in[15];
    const float* wp     = (const float*)d_in[16];
    const float* wx     = (const float*)d_in[17];
    const float* fc_w   = (const float*)d_in[18];
    const float* fc_b   = (const float*)d_in[19];
    float* out = (float*)d_out;

    // Byte allocator over d_ws, 256B aligned. Total ~174 MB (all fp32).
    char* wsc = (char*)d_ws;
    size_t off = 0;
    auto alloc = [&](size_t bytes) {
        void* p = wsc + off;
        off += (bytes + 255) & ~(size_t)255;
        return (float*)p;
    };
    float* Y      = alloc((size_t)B * SP * H * sizeof(float));   // masked premise outputs [B,SP,H]
    float* first  = alloc((size_t)B * SP * H * sizeof(float));   // Y @ wy
    float* outh   = alloc((size_t)SH * B * H * sizeof(float));   // masked hyp outputs [SH,B,H]
    float* g      = alloc((size_t)B * G4H * sizeof(float));      // gate pre-activations
    float* hbuf   = alloc((size_t)B * H * sizeof(float));        // LSTM h (unmasked)
    float* cbuf   = alloc((size_t)B * H * sizeof(float));        // LSTM c (unmasked, premise)
    float* hm     = alloc((size_t)B * H * sizeof(float));        // masked-carry h
    float* cm     = alloc((size_t)B * H * sizeof(float));        // masked-carry c (-> hyp c state)
    float* r      = alloc((size_t)B * H * sizeof(float));
    float* second = alloc((size_t)B * H * sizeof(float));
    float* rwt    = alloc((size_t)B * H * sizeof(float));
    float* pre    = alloc((size_t)B * H * sizeof(float));
    float* sc     = alloc((size_t)B * SP * sizeof(float));
    (void)ws_size; (void)in_sizes; (void)n_in; (void)out_size;

    // zero h, c, hmask, cmask (contiguous, each 512 KB so alignment pads are 0)
    hipMemsetAsync(hbuf, 0, (size_t)4 * B * H * sizeof(float), stream);

    dim3 gGates(G4H / 64, B / 32);   // (64, 4)
    const int cellBlocks = (B * H) / 256;

    // -------- premise LSTM --------
    for (int t = 0; t < SP; ++t) {
        gates_kernel<<<gGates, 256, 0, stream>>>(prem, t, SP, emb, hbuf,
                                                 w_ih_p, w_hh_p, b_ih_p, b_hh_p, g);
        lstm_cell_kernel<<<cellBlocks, 256, 0, stream>>>(g, hbuf, cbuf, hm, cm,
                                                         Y, 1, prem, t, SP);
    }

    // -------- hypothesis LSTM: h=0, c=c_last (in cm), fresh masked carry --------
    hipMemsetAsync(hbuf, 0, (size_t)B * H * sizeof(float), stream);
    hipMemsetAsync(hm,   0, (size_t)B * H * sizeof(float), stream);
    for (int t = 0; t < SH; ++t) {
        gates_kernel<<<gGates, 256, 0, stream>>>(hyp, t, SH, emb, hbuf,
                                                 w_ih_h, w_hh_h, b_ih_h, b_hh_h, g);
        lstm_cell_kernel<<<cellBlocks, 256, 0, stream>>>(g, hbuf, cm, hm, nullptr,
                                                         outh, 0, hyp, t, SH);
    }
    // hm now holds out_h_last; outh holds the masked hyp sequence.

    // -------- first = Y @ wy  [16384,1024] x [1024,1024] --------
    {
        dim3 gF(H / 64, (B * SP) / 32);
        sgemm_kernel<false><<<gF, 256, 0, stream>>>(Y, H, wy, H, first, H, B * SP, H, H);
    }

    // -------- attention scan --------
    hipMemsetAsync(r, 0, (size_t)B * H * sizeof(float), stream);
    dim3 gS(H / 64, B / 32);         // (16, 4)
    for (int t = 0; t < SH; ++t) {
        const float* ht = outh + (size_t)t * B * H;
        sgemm_kernel<false><<<gS, 256, 0, stream>>>(ht, H, wh, H, second, H, B, H, H);
        sgemm_kernel<true ><<<gS, 256, 0, stream>>>(r,  H, wr, H, second, H, B, H, H);
        sgemm_kernel<false><<<gS, 256, 0, stream>>>(r,  H, wt, H, rwt,    H, B, H, H);
        score_kernel<<<B * SP, 256, 0, stream>>>(first, second, wv, prem, sc);
        softmax_kernel<<<B, 128, 0, stream>>>(sc);
        r_update_kernel<<<B, 256, 0, stream>>>(sc, Y, rwt, hyp, t, r);
    }

    // -------- final projection + softmax --------
    sgemm_kernel<false><<<gS, 256, 0, stream>>>(r,  H, wp, H, pre, H, B, H, H);
    sgemm_kernel<true ><<<gS, 256, 0, stream>>>(hm, H, wx, H, pre, H, B, H, H);
    final_kernel<<<B, 256, 0, stream>>>(pre, fc_w, fc_b, out);
}

// Round 6
// 18758.542 us; speedup vs baseline: 2.5870x; 2.5870x over previous
//
#include <hip/hip_runtime.h>

// Problem dims (fixed by the reference)
constexpr int B  = 128;
constexpr int SP = 128;
constexpr int SH = 64;
constexpr int H  = 1024;
constexpr int E  = 300;
constexpr int NC = 4;
constexpr int G4H  = 4 * H;     // 4096
constexpr int KCAT = E + H;     // 1324

__device__ __forceinline__ float sigf(float x) { return 1.0f / (1.0f + __expf(-x)); }
__device__ __forceinline__ float tanh_fast(float x) {
    float e = __expf(2.0f * x);
    return 1.0f - 2.0f / (e + 1.0f);
}

// ---------------------------------------------------------------------------
// 64x64-tile SGEMM, BK=16, 256 threads, TM=TN=4, reg->LDS double buffered.
// C[M,N] = A[M,K] @ Bw[K,N]; lda=K, ldb=N, ldc=N. M%64==0, N%64==0.
// ---------------------------------------------------------------------------
__global__ __launch_bounds__(256)
void gemm64_kernel(const float* __restrict__ A, const float* __restrict__ Bw,
                   float* __restrict__ C, int M, int N, int K)
{
    const int tid = threadIdx.x;
    const int tx = tid & 15, ty = tid >> 4;      // compute mapping
    const int n0 = blockIdx.x * 64, m0 = blockIdx.y * 64;
    __shared__ float As[2][16][68];
    __shared__ float Bs[2][16][68];
    const int ka = tid & 15, ma = tid >> 4;      // A staging: col ka, rows ma+16r
    const int nb = tid & 63, kb = tid >> 6;      // B staging: col nb, rows kb+4r

    float ra[4], rb[4];
    auto ldA = [&](int k0, int r) -> float {
        int k = k0 + ka;
        return (k < K) ? A[(size_t)(m0 + ma + 16 * r) * K + k] : 0.f;
    };
    auto ldB = [&](int k0, int r) -> float {
        int k = k0 + kb + 4 * r;
        return (k < K) ? Bw[(size_t)k * N + n0 + nb] : 0.f;
    };

    float acc[4][4] = {};
#pragma unroll
    for (int r = 0; r < 4; ++r) { ra[r] = ldA(0, r); rb[r] = ldB(0, r); }
#pragma unroll
    for (int r = 0; r < 4; ++r) { As[0][ka][ma + 16 * r] = ra[r]; Bs[0][kb + 4 * r][nb] = rb[r]; }
    __syncthreads();

    const int NKT = (K + 15) / 16;
    for (int kt = 0; kt < NKT; ++kt) {
        const int buf = kt & 1;
        if (kt + 1 < NKT) {
            int k0 = (kt + 1) * 16;
#pragma unroll
            for (int r = 0; r < 4; ++r) { ra[r] = ldA(k0, r); rb[r] = ldB(k0, r); }
        }
#pragma unroll
        for (int kk = 0; kk < 16; ++kk) {
            float4 a4 = *(const float4*)&As[buf][kk][ty * 4];
            float4 b4 = *(const float4*)&Bs[buf][kk][tx * 4];
            float av[4] = {a4.x, a4.y, a4.z, a4.w};
            float bv[4] = {b4.x, b4.y, b4.z, b4.w};
#pragma unroll
            for (int i = 0; i < 4; ++i)
#pragma unroll
                for (int j = 0; j < 4; ++j) acc[i][j] += av[i] * bv[j];
        }
        if (kt + 1 < NKT) {
            const int nbuf = buf ^ 1;
#pragma unroll
            for (int r = 0; r < 4; ++r) { As[nbuf][ka][ma + 16 * r] = ra[r]; Bs[nbuf][kb + 4 * r][nb] = rb[r]; }
            __syncthreads();
        }
    }
#pragma unroll
    for (int i = 0; i < 4; ++i) {
        int m = m0 + ty * 4 + i;
        float4 v = make_float4(acc[i][0], acc[i][1], acc[i][2], acc[i][3]);
        *(float4*)&C[(size_t)m * N + n0 + tx * 4] = v;
    }
}

// ---------------------------------------------------------------------------
// Fused LSTM step: g = [emb_gather | h_in] @ [w_ih | w_hh]^T (+ biases),
// then the pointwise cell + masked-carry, all in one kernel.
// Output tile = 32 rows x (16 hidden-units x 4 gates): each thread ends up
// holding all 4 gates for its (m, k) -> thread-local cell epilogue.
// h ping-pong (h_in read-only, h_out written) avoids the read/write race.
// Grid (64, 4), 256 threads.
// ---------------------------------------------------------------------------
template<int PREMISE>
__global__ __launch_bounds__(256)
void lstm_step_kernel(const int* __restrict__ tokens, int t, int S,
                      const float* __restrict__ emb,
                      const float* __restrict__ w_ih,   // [4H][E]
                      const float* __restrict__ w_hh,   // [4H][H]
                      const float* __restrict__ b_ih,
                      const float* __restrict__ b_hh,
                      const float* __restrict__ h_in,
                      float* __restrict__ h_out,
                      float* __restrict__ c,
                      float* __restrict__ hmask,
                      float* __restrict__ cmask,
                      float* __restrict__ seq_out)
{
    const int tid = threadIdx.x;
    const int tx = tid & 15;          // k within tile (compute)
    const int ty = tid >> 4;          // m-pair (compute)
    const int k0 = blockIdx.x * 16;   // hidden-unit tile base
    const int m0 = blockIdx.y * 32;

    __shared__ float As[2][16][34];   // [q][m] m-stride 34 (float2-aligned)
    __shared__ float Bs[2][16][68];   // [q][k*4+gate] row-stride 68 (float4-aligned)

    const int sq = tid & 15;          // staging q index
    const int sr = tid >> 4;          // staging row/k index

    const int arow0 = m0 + sr;
    const int arow1 = m0 + sr + 16;
    const int tok0 = tokens[arow0 * S + t];
    const int tok1 = tokens[arow1 * S + t];

    float ra[2], rb[4];
    auto ldA = [&](int q0, int r) -> float {
        int q = q0 + sq;
        if (q < E)     return emb[(size_t)(r == 0 ? tok0 : tok1) * E + q];
        if (q < KCAT)  return h_in[(size_t)(r == 0 ? arow0 : arow1) * H + (q - E)];
        return 0.f;
    };
    auto ldB = [&](int q0, int g) -> float {
        int q = q0 + sq;
        int n = (g << 10) + k0 + sr;           // gate g, hidden unit k0+sr
        if (q < E)     return w_ih[(size_t)n * E + q];
        if (q < KCAT)  return w_hh[(size_t)n * H + (q - E)];
        return 0.f;
    };

    float acc[2][4] = {};
    ra[0] = ldA(0, 0); ra[1] = ldA(0, 1);
#pragma unroll
    for (int g = 0; g < 4; ++g) rb[g] = ldB(0, g);
    As[0][sq][sr] = ra[0]; As[0][sq][sr + 16] = ra[1];
#pragma unroll
    for (int g = 0; g < 4; ++g) Bs[0][sq][sr * 4 + g] = rb[g];
    __syncthreads();

    constexpr int NKT = (KCAT + 15) / 16;      // 83
    for (int kt = 0; kt < NKT; ++kt) {
        const int buf = kt & 1;
        if (kt + 1 < NKT) {
            int q0 = (kt + 1) * 16;
            ra[0] = ldA(q0, 0); ra[1] = ldA(q0, 1);
#pragma unroll
            for (int g = 0; g < 4; ++g) rb[g] = ldB(q0, g);
        }
#pragma unroll
        for (int qq = 0; qq < 16; ++qq) {
            float2 a2 = *(const float2*)&As[buf][qq][ty * 2];
            float4 b4 = *(const float4*)&Bs[buf][qq][tx * 4];
            acc[0][0] += a2.x * b4.x; acc[0][1] += a2.x * b4.y;
            acc[0][2] += a2.x * b4.z; acc[0][3] += a2.x * b4.w;
            acc[1][0] += a2.y * b4.x; acc[1][1] += a2.y * b4.y;
            acc[1][2] += a2.y * b4.z; acc[1][3] += a2.y * b4.w;
        }
        if (kt + 1 < NKT) {
            const int nbuf = buf ^ 1;
            As[nbuf][sq][sr] = ra[0]; As[nbuf][sq][sr + 16] = ra[1];
#pragma unroll
            for (int g = 0; g < 4; ++g) Bs[nbuf][sq][sr * 4 + g] = rb[g];
            __syncthreads();
        }
    }

    // ---- cell epilogue (thread-local: owns k = k0+tx, m = m0+ty*2+{0,1}) ----
    const int k = k0 + tx;
    float bsum[4];
#pragma unroll
    for (int g = 0; g < 4; ++g) bsum[g] = b_ih[g * H + k] + b_hh[g * H + k];
#pragma unroll
    for (int i = 0; i < 2; ++i) {
        int m = m0 + ty * 2 + i;
        size_t idx = (size_t)m * H + k;
        float i_ = sigf(acc[i][0] + bsum[0]);
        float f_ = sigf(acc[i][1] + bsum[1]);
        float g_ = tanh_fast(acc[i][2] + bsum[2]);
        float o_ = sigf(acc[i][3] + bsum[3]);
        float c2 = f_ * c[idx] + i_ * g_;
        float h2 = o_ * tanh_fast(c2);
        c[idx] = c2;
        h_out[idx] = h2;
        float mt = (tokens[m * S + t] != 0) ? 1.f : 0.f;
        float hmv = mt * h2 + (1.f - mt) * hmask[idx];
        hmask[idx] = hmv;
        if (PREMISE) {
            float cmv = mt * c2 + (1.f - mt) * cmask[idx];
            cmask[idx] = cmv;
            seq_out[((size_t)m * SP + t) * H + k] = hmv;   // Y [B][SP][H]
        } else {
            seq_out[((size_t)t * B + m) * H + k] = hmv;    // outh [SH][B][H]
        }
    }
}

// ---------------------------------------------------------------------------
// Skinny GEMM (M=128): tile 32x64, BK=16, 256 threads, TM=2 TN=4, dbuf.
// Dual mode: bx < ntiles -> C1 = A@B1 tile; else C2 = A@B2 tile.
// ---------------------------------------------------------------------------
template<bool ACC>
__global__ __launch_bounds__(256)
void skinny_kernel(const float* __restrict__ A,
                   const float* __restrict__ B1, float* __restrict__ C1,
                   const float* __restrict__ B2, float* __restrict__ C2,
                   int K, int N, int ntiles)
{
    const int tid = threadIdx.x;
    const int tx = tid & 15, ty = tid >> 4;
    const int bx = blockIdx.x;
    const float* Bw = (bx < ntiles) ? B1 : B2;
    float* C       = (bx < ntiles) ? C1 : C2;
    const int n0 = ((bx < ntiles) ? bx : bx - ntiles) * 64;
    const int m0 = blockIdx.y * 32;

    __shared__ float As[2][16][34];
    __shared__ float Bs[2][16][68];
    const int sq = tid & 15, sm = tid >> 4;    // A staging
    const int nb = tid & 63, kb = tid >> 6;    // B staging

    float ra[2], rb[4];
    auto ldA = [&](int k0, int r) -> float {
        return A[(size_t)(m0 + sm + 16 * r) * K + k0 + sq];
    };
    auto ldB = [&](int k0, int r) -> float {
        return Bw[(size_t)(k0 + kb + 4 * r) * N + n0 + nb];
    };

    float acc[2][4] = {};
    ra[0] = ldA(0, 0); ra[1] = ldA(0, 1);
#pragma unroll
    for (int r = 0; r < 4; ++r) rb[r] = ldB(0, r);
    As[0][sq][sm] = ra[0]; As[0][sq][sm + 16] = ra[1];
#pragma unroll
    for (int r = 0; r < 4; ++r) Bs[0][kb + 4 * r][nb] = rb[r];
    __syncthreads();

    const int NKT = K / 16;
    for (int kt = 0; kt < NKT; ++kt) {
        const int buf = kt & 1;
        if (kt + 1 < NKT) {
            int k0 = (kt + 1) * 16;
            ra[0] = ldA(k0, 0); ra[1] = ldA(k0, 1);
#pragma unroll
            for (int r = 0; r < 4; ++r) rb[r] = ldB(k0, r);
        }
#pragma unroll
        for (int qq = 0; qq < 16; ++qq) {
            float2 a2 = *(const float2*)&As[buf][qq][ty * 2];
            float4 b4 = *(const float4*)&Bs[buf][qq][tx * 4];
            acc[0][0] += a2.x * b4.x; acc[0][1] += a2.x * b4.y;
            acc[0][2] += a2.x * b4.z; acc[0][3] += a2.x * b4.w;
            acc[1][0] += a2.y * b4.x; acc[1][1] += a2.y * b4.y;
            acc[1][2] += a2.y * b4.z; acc[1][3] += a2.y * b4.w;
        }
        if (kt + 1 < NKT) {
            const int nbuf = buf ^ 1;
            As[nbuf][sq][sm] = ra[0]; As[nbuf][sq][sm + 16] = ra[1];
#pragma unroll
            for (int r = 0; r < 4; ++r) Bs[nbuf][kb + 4 * r][nb] = rb[r];
            __syncthreads();
        }
    }
#pragma unroll
    for (int i = 0; i < 2; ++i) {
        int m = m0 + ty * 2 + i;
        float* cp = &C[(size_t)m * N + n0 + tx * 4];
        float4 v = make_float4(acc[i][0], acc[i][1], acc[i][2], acc[i][3]);
        if (ACC) {
            float4 o = *(const float4*)cp;
            v.x += o.x; v.y += o.y; v.z += o.z; v.w += o.w;
        }
        *(float4*)cp = v;
    }
}

// ---------------------------------------------------------------------------
// score: s[b,p] = sum_h tanh(first[b,p,h] + hsec_t[b,h] + secr[b,h]) * w[h]
//        + (-1000 on premise pads). Wave shuffle reduce.
// ---------------------------------------------------------------------------
__global__ __launch_bounds__(256)
void score_kernel(const float* __restrict__ first,
                  const float* __restrict__ hsec_t,
                  const float* __restrict__ secr,
                  const float* __restrict__ w,
                  const int* __restrict__ ptoks,
                  float* __restrict__ s)
{
    const int bp = blockIdx.x;
    const int b = bp >> 7;
    const float* fr = first + (size_t)bp * H;
    const float* hs = hsec_t + (size_t)b * H;
    const float* sr = secr + (size_t)b * H;
    float acc = 0.f;
#pragma unroll
    for (int j = 0; j < 4; ++j) {
        int k = threadIdx.x + j * 256;
        acc += tanh_fast(fr[k] + hs[k] + sr[k]) * w[k];
    }
    for (int off = 32; off > 0; off >>= 1) acc += __shfl_down(acc, off);
    __shared__ float red[4];
    if ((threadIdx.x & 63) == 0) red[threadIdx.x >> 6] = acc;
    __syncthreads();
    if (threadIdx.x == 0) {
        float v = red[0] + red[1] + red[2] + red[3];
        int p = bp & 127;
        s[bp] = v + ((ptoks[b * SP + p] != 0) ? 0.f : -1000.f);
    }
}

// ---------------------------------------------------------------------------
// r_update with fused softmax: alpha = softmax(s[b,:]);
// r_new = alpha @ Y[b] + tanh(rwt[b]); masked carry into r.
// ---------------------------------------------------------------------------
__global__ __launch_bounds__(256)
void r_update_kernel(const float* __restrict__ s,
                     const float* __restrict__ Y,
                     const float* __restrict__ rwt,
                     const int* __restrict__ htoks, int t,
                     float* __restrict__ r)
{
    const int b = blockIdx.x, tid = threadIdx.x;
    __shared__ float al[SP];
    __shared__ float red[SP];
    if (tid < SP) { al[tid] = s[b * SP + tid]; red[tid] = al[tid]; }
    __syncthreads();
    for (int off = 64; off > 0; off >>= 1) {
        if (tid < off) red[tid] = fmaxf(red[tid], red[tid + off]);
        __syncthreads();
    }
    float mx = red[0];
    __syncthreads();
    if (tid < SP) { al[tid] = __expf(al[tid] - mx); red[tid] = al[tid]; }
    __syncthreads();
    for (int off = 64; off > 0; off >>= 1) {
        if (tid < off) red[tid] += red[tid + off];
        __syncthreads();
    }
    float inv = 1.f / red[0];
    __syncthreads();
    if (tid < SP) al[tid] *= inv;
    __syncthreads();

    float acc[4] = {0.f, 0.f, 0.f, 0.f};
    const float* Yb = Y + (size_t)b * SP * H;
    for (int p = 0; p < SP; ++p) {
        float a = al[p];
        const float* yr = Yb + (size_t)p * H;
#pragma unroll
        for (int j = 0; j < 4; ++j) acc[j] += a * yr[tid + j * 256];
    }
    float mt = (htoks[b * SH + t] != 0) ? 1.f : 0.f;
#pragma unroll
    for (int j = 0; j < 4; ++j) {
        int k = tid + j * 256;
        float rnew = acc[j] + tanh_fast(rwt[(size_t)b * H + k]);
        r[(size_t)b * H + k] = mt * rnew + (1.f - mt) * r[(size_t)b * H + k];
    }
}

// logits -> softmax over 4 classes -> fp32 out
__global__ __launch_bounds__(256)
void final_kernel(const float* __restrict__ pre,
                  const float* __restrict__ fc_w,
                  const float* __restrict__ fc_b,
                  float* __restrict__ out)
{
    int b = blockIdx.x;
    float acc[NC] = {0.f, 0.f, 0.f, 0.f};
    for (int k = threadIdx.x; k < H; k += 256) {
        float hs = tanh_fast(pre[(size_t)b * H + k]);
#pragma unroll
        for (int cc = 0; cc < NC; ++cc) acc[cc] += hs * fc_w[cc * H + k];
    }
    __shared__ float red[NC][256];
#pragma unroll
    for (int cc = 0; cc < NC; ++cc) red[cc][threadIdx.x] = acc[cc];
    __syncthreads();
    for (int off = 128; off > 0; off >>= 1) {
        if (threadIdx.x < off)
#pragma unroll
            for (int cc = 0; cc < NC; ++cc)
                red[cc][threadIdx.x] += red[cc][threadIdx.x + off];
        __syncthreads();
    }
    if (threadIdx.x == 0) {
        float l[NC], mx = -1e30f;
#pragma unroll
        for (int cc = 0; cc < NC; ++cc) { l[cc] = red[cc][0] + fc_b[cc]; mx = fmaxf(mx, l[cc]); }
        float sum = 0.f;
#pragma unroll
        for (int cc = 0; cc < NC; ++cc) { l[cc] = __expf(l[cc] - mx); sum += l[cc]; }
#pragma unroll
        for (int cc = 0; cc < NC; ++cc) out[b * NC + cc] = l[cc] / sum;
    }
}

extern "C" void kernel_launch(void* const* d_in, const int* in_sizes, int n_in,
                              void* d_out, int out_size, void* d_ws, size_t ws_size,
                              hipStream_t stream)
{
    const int*   prem   = (const int*)d_in[0];
    const int*   hyp    = (const int*)d_in[1];
    const float* emb    = (const float*)d_in[2];
    const float* w_ih_p = (const float*)d_in[3];
    const float* w_hh_p = (const float*)d_in[4];
    const float* b_ih_p = (const float*)d_in[5];
    const float* b_hh_p = (const float*)d_in[6];
    const float* w_ih_h = (const float*)d_in[7];
    const float* w_hh_h = (const float*)d_in[8];
    const float* b_ih_h = (const float*)d_in[9];
    const float* b_hh_h = (const float*)d_in[10];
    const float* wy     = (const float*)d_in[11];
    const float* wh     = (const float*)d_in[12];
    const float* wr     = (const float*)d_in[13];
    const float* wv     = (const float*)d_in[14];
    const float* wt     = (const float*)d_in[15];
    const float* wp     = (const float*)d_in[16];
    const float* wx     = (const float*)d_in[17];
    const float* fc_w   = (const float*)d_in[18];
    const float* fc_b   = (const float*)d_in[19];
    float* out = (float*)d_out;
    (void)in_sizes; (void)n_in; (void)out_size; (void)ws_size;

    char* wsc = (char*)d_ws;
    size_t off = 0;
    auto alloc = [&](size_t bytes) {
        void* p = wsc + off;
        off += (bytes + 255) & ~(size_t)255;
        return (float*)p;
    };
    float* Y     = alloc((size_t)B * SP * H * 4);   // [B][SP][H] masked premise outputs
    float* first = alloc((size_t)B * SP * H * 4);   // Y @ wy
    float* outh  = alloc((size_t)SH * B * H * 4);   // [SH][B][H] masked hyp outputs
    float* hsec  = alloc((size_t)SH * B * H * 4);   // outh @ wh (hoisted)
    // h0,h1,c,hm,cm contiguous (zeroed together)
    float* h0    = alloc((size_t)B * H * 4);
    float* h1    = alloc((size_t)B * H * 4);
    float* cbuf  = alloc((size_t)B * H * 4);
    float* hm    = alloc((size_t)B * H * 4);
    float* cm    = alloc((size_t)B * H * 4);
    float* r     = alloc((size_t)B * H * 4);
    float* secr  = alloc((size_t)B * H * 4);        // r @ wr
    float* rwt   = alloc((size_t)B * H * 4);        // r @ wt
    float* pre   = alloc((size_t)B * H * 4);
    float* sc    = alloc((size_t)B * SP * 4);

    const dim3 gStep(64, 4);          // lstm_step grid
    const size_t BH = (size_t)B * H * sizeof(float);

    // zero h0,h1,c,hm,cm (contiguous, exact multiples of 256B -> no gaps)
    hipMemsetAsync(h0, 0, 5 * BH, stream);

    // -------- premise LSTM (fused step, h ping-pong) --------
    {
        float* hin = h0; float* hout = h1;
        for (int t = 0; t < SP; ++t) {
            lstm_step_kernel<1><<<gStep, 256, 0, stream>>>(
                prem, t, SP, emb, w_ih_p, w_hh_p, b_ih_p, b_hh_p,
                hin, hout, cbuf, hm, cm, Y);
            float* tmp = hin; hin = hout; hout = tmp;
        }
    }

    // -------- hypothesis LSTM: h=0, c = cm (masked last premise cell) --------
    hipMemsetAsync(h0, 0, 2 * BH, stream);   // h0,h1
    hipMemsetAsync(hm, 0, BH, stream);
    {
        float* hin = h0; float* hout = h1;
        for (int t = 0; t < SH; ++t) {
            lstm_step_kernel<0><<<gStep, 256, 0, stream>>>(
                hyp, t, SH, emb, w_ih_h, w_hh_h, b_ih_h, b_hh_h,
                hin, hout, cm, hm, nullptr, outh);
            float* tmp = hin; hin = hout; hout = tmp;
        }
    }
    // hm = out_h_last

    // -------- hoisted GEMMs --------
    gemm64_kernel<<<dim3(H / 64, (B * SP) / 64), 256, 0, stream>>>(Y, wy, first, B * SP, H, H);
    gemm64_kernel<<<dim3(H / 64, (SH * B) / 64), 256, 0, stream>>>(outh, wh, hsec, SH * B, H, H);

    // -------- attention scan --------
    hipMemsetAsync(r, 0, BH, stream);
    for (int t = 0; t < SH; ++t) {
        skinny_kernel<false><<<dim3(32, 4), 256, 0, stream>>>(r, wr, secr, wt, rwt, H, H, 16);
        score_kernel<<<B * SP, 256, 0, stream>>>(first, hsec + (size_t)t * B * H, secr, wv, prem, sc);
        r_update_kernel<<<B, 256, 0, stream>>>(sc, Y, rwt, hyp, t, r);
    }

    // -------- final projection + softmax --------
    skinny_kernel<false><<<dim3(16, 4), 256, 0, stream>>>(r,  wp, pre, nullptr, nullptr, H, H, 16);
    skinny_kernel<true ><<<dim3(16, 4), 256, 0, stream>>>(hm, wx, pre, nullptr, nullptr, H, H, 16);
    final_kernel<<<B, 256, 0, stream>>>(pre, fc_w, fc_b, out);
}